// Round 1
// baseline (1731.206 us; speedup 1.0000x reference)
//
#include <hip/hip_runtime.h>

// AttentionalGraphAggregation on MI355X.
// Pipeline: memset -> gate GEMM (bf16 MFMA) -> seg max -> exp+denom -> transform GEMM + scatter.
// x read twice (1 GB each) => HBM-bound, floor ~330 us.

using bf16x8 = __attribute__((ext_vector_type(8))) short;   // 8 bf16 bit-patterns (4 VGPRs)
using short8 = __attribute__((ext_vector_type(8))) short;
using f32x16 = __attribute__((ext_vector_type(16))) float;  // 32x32 MFMA accumulator

// float -> bf16 bits, round-to-nearest-even (inputs are finite)
__device__ inline short f2b(float f) {
  unsigned u = __builtin_bit_cast(unsigned, f);
  unsigned r = (u + 0x7FFFu + ((u >> 16) & 1u)) >> 16;
  return (short)(unsigned short)r;
}

// ---------------------------------------------------------------------------
// Kernel A: gate[i] = relu(x@W1+b1) @ W2 + b2   (x: [N,256], W1: [256,128])
// Block = 512 thr = 8 waves. Batch = 64 rows. wave w: rowtile = w>>2 (32 rows),
// col strip = (w&3)*32 of HID=128. W1 fragments register-resident.
// MFMA 32x32x16 bf16 layouts (m74/m101-verified C/D; standard A/B):
//   A[m][k]: m=lane&31, k=(lane>>5)*8+j   B[k][n]: n=lane&31, k=(lane>>5)*8+j
//   C row = (reg&3)+8*(reg>>2)+4*(lane>>5), col = lane&31
// ---------------------------------------------------------------------------
__global__ __launch_bounds__(512) void gate_kernel(
    const float* __restrict__ x, const float* __restrict__ W1,
    const float* __restrict__ b1, const float* __restrict__ W2,
    const float* __restrict__ b2p, float* __restrict__ gate, int nbatch)
{
  __shared__ unsigned short xt[64][264];  // bf16 bits; stride 264 (16B aligned, breaks worst conflicts)
  __shared__ float gpart[4][64];
  const int tid = threadIdx.x;
  const int wave = tid >> 6, lane = tid & 63;
  const int half = lane >> 5, l32 = lane & 31;
  const int strip = (wave & 3) * 32, rowtile = wave >> 2;
  const int col = strip + l32;  // 0..127

  bf16x8 bf[16];
#pragma unroll
  for (int t = 0; t < 16; ++t)
#pragma unroll
    for (int j = 0; j < 8; ++j)
      bf[t][j] = f2b(W1[(t * 16 + half * 8 + j) * 128 + col]);
  const float b1v = b1[col];
  const float w2v = W2[col];

  for (int batch = blockIdx.x; batch < nbatch; batch += gridDim.x) {
    const int r0 = batch * 64;
    __syncthreads();
    {
      // stage 64 rows of x as bf16: thread -> row tid>>3, 32 cols at (tid&7)*32
      const int tr = tid >> 3, c0 = (tid & 7) * 32;
      const float4* xp = (const float4*)(x + (size_t)(r0 + tr) * 256 + c0);
      short8* dst = (short8*)&xt[tr][c0];
#pragma unroll
      for (int q = 0; q < 4; ++q) {
        float4 f0 = xp[2 * q], f1 = xp[2 * q + 1];
        short8 w;
        w[0] = f2b(f0.x); w[1] = f2b(f0.y); w[2] = f2b(f0.z); w[3] = f2b(f0.w);
        w[4] = f2b(f1.x); w[5] = f2b(f1.y); w[6] = f2b(f1.z); w[7] = f2b(f1.w);
        dst[q] = w;
      }
    }
    __syncthreads();
    f32x16 acc = (f32x16)0.0f;
#pragma unroll
    for (int t = 0; t < 16; ++t) {
      bf16x8 a = *(const bf16x8*)&xt[rowtile * 32 + l32][t * 16 + half * 8];
      acc = __builtin_amdgcn_mfma_f32_32x32x16_bf16(a, bf[t], acc, 0, 0, 0);
    }
    // epilogue: h=relu(acc+b1), partial gate = h*W2[col], reduce over 32 cols (half-wave)
#pragma unroll
    for (int reg = 0; reg < 16; ++reg) {
      const int r = (reg & 3) + 8 * (reg >> 2) + 4 * half;
      float h = acc[reg] + b1v;
      h = h > 0.f ? h : 0.f;
      float pv = h * w2v;
#pragma unroll
      for (int d = 1; d < 32; d <<= 1) pv += __shfl_xor(pv, d, 64);
      if (l32 == 0) gpart[wave & 3][rowtile * 32 + r] = pv;
    }
    __syncthreads();
    if (tid < 64)
      gate[r0 + tid] = gpart[0][tid] + gpart[1][tid] + gpart[2][tid] + gpart[3][tid] + b2p[0];
  }
}

// ---------------------------------------------------------------------------
// Kernel B: per-segment max via wave-segmented scan + atomicMax on monotone uint
// ---------------------------------------------------------------------------
__global__ __launch_bounds__(256) void seg_max_kernel(
    const float* __restrict__ gate, const int* __restrict__ idx,
    unsigned* __restrict__ smax_u, int N)
{
  const int i = blockIdx.x * 256 + threadIdx.x;
  const int lane = threadIdx.x & 63;
  float g = -__builtin_inff();
  int s = -1;
  if (i < N) { g = gate[i]; s = idx[i]; }
#pragma unroll
  for (int d = 1; d < 64; d <<= 1) {
    float og = __shfl_up(g, d, 64);
    int os = __shfl_up(s, d, 64);
    if (lane >= d && os == s) g = fmaxf(g, og);
  }
  const int ns = __shfl_down(s, 1, 64);
  const bool last = (lane == 63) || (ns != s);
  if (i < N && last) {
    unsigned u = __builtin_bit_cast(unsigned, g);
    u = (u & 0x80000000u) ? ~u : (u | 0x80000000u);  // order-preserving map; 0 = empty sentinel
    atomicMax(&smax_u[s], u);
  }
}

// ---------------------------------------------------------------------------
// Kernel C: e[i] = exp(gate-max); denom[s] += run-sum (segmented scan + atomicAdd)
// ---------------------------------------------------------------------------
__global__ __launch_bounds__(256) void seg_denom_kernel(
    const float* __restrict__ gate, const int* __restrict__ idx,
    const unsigned* __restrict__ smax_u, float* __restrict__ e,
    float* __restrict__ denom, int N)
{
  const int i = blockIdx.x * 256 + threadIdx.x;
  const int lane = threadIdx.x & 63;
  float ev = 0.f;
  int s = -1;
  if (i < N) {
    s = idx[i];
    const unsigned u = smax_u[s];
    const unsigned b = (u & 0x80000000u) ? (u ^ 0x80000000u) : ~u;
    const float m = __builtin_bit_cast(float, b);
    ev = __expf(gate[i] - m);
    e[i] = ev;
  }
#pragma unroll
  for (int d = 1; d < 64; d <<= 1) {
    float oe = __shfl_up(ev, d, 64);
    int os = __shfl_up(s, d, 64);
    if (lane >= d && os == s) ev += oe;
  }
  const int ns = __shfl_down(s, 1, 64);
  const bool last = (lane == 63) || (ns != s);
  if (i < N && last) atomicAdd(&denom[s], ev);
}

// ---------------------------------------------------------------------------
// Kernel D: t = relu(x@Wt+bt); out[seg] += alpha*t, run-batched segmented scatter.
// Block = 512 thr = 8 waves; each wave owns a 32-col strip of OUT=256.
// Batch = 32 rows (sorted => ~1.5 runs/batch => ~1 atomicAdd per (run,col)).
// ---------------------------------------------------------------------------
__global__ __launch_bounds__(512) void transform_kernel(
    const float* __restrict__ x, const int* __restrict__ idx,
    const float* __restrict__ Wt, const float* __restrict__ bt,
    const float* __restrict__ e, const float* __restrict__ denom,
    float* __restrict__ out, int nbatch)
{
  __shared__ unsigned short xt[32][264];
  __shared__ float alpha_s[32];
  __shared__ int seg_s[32];
  const int tid = threadIdx.x;
  const int wave = tid >> 6, lane = tid & 63;
  const int half = lane >> 5, l32 = lane & 31;
  const int col = wave * 32 + l32;  // 0..255

  bf16x8 bf[16];
#pragma unroll
  for (int t = 0; t < 16; ++t)
#pragma unroll
    for (int j = 0; j < 8; ++j)
      bf[t][j] = f2b(Wt[(t * 16 + half * 8 + j) * 256 + col]);
  const float btv = bt[col];

  for (int batch = blockIdx.x; batch < nbatch; batch += gridDim.x) {
    const int r0 = batch * 32;
    __syncthreads();
    {
      // stage 32 rows: thread -> row tid>>4, 16 cols at (tid&15)*16
      const int tr = tid >> 4, c0 = (tid & 15) * 16;
      const float4* xp = (const float4*)(x + (size_t)(r0 + tr) * 256 + c0);
      short8* dst = (short8*)&xt[tr][c0];
#pragma unroll
      for (int q = 0; q < 2; ++q) {
        float4 f0 = xp[2 * q], f1 = xp[2 * q + 1];
        short8 w;
        w[0] = f2b(f0.x); w[1] = f2b(f0.y); w[2] = f2b(f0.z); w[3] = f2b(f0.w);
        w[4] = f2b(f1.x); w[5] = f2b(f1.y); w[6] = f2b(f1.z); w[7] = f2b(f1.w);
        dst[q] = w;
      }
    }
    if (tid < 32) {
      const int s = idx[r0 + tid];
      seg_s[tid] = s;
      alpha_s[tid] = e[r0 + tid] / fmaxf(denom[s], 1e-16f);
    }
    __syncthreads();
    f32x16 acc = (f32x16)0.0f;
#pragma unroll
    for (int t = 0; t < 16; ++t) {
      bf16x8 a = *(const bf16x8*)&xt[l32][t * 16 + half * 8];
      acc = __builtin_amdgcn_mfma_f32_32x32x16_bf16(a, bf[t], acc, 0, 0, 0);
    }
    float v[16];
#pragma unroll
    for (int reg = 0; reg < 16; ++reg) {
      const int r = (reg & 3) + 8 * (reg >> 2) + 4 * half;
      float tv = acc[reg] + btv;
      tv = tv > 0.f ? tv : 0.f;
      v[reg] = tv * alpha_s[r];
    }
    // per-run reduce over rows then one atomicAdd per (run, col)
    int pos = 0;
    while (pos < 32) {
      const int s = seg_s[pos];
      int end = pos + 1;
      while (end < 32 && seg_s[end] == s) ++end;
      float part = 0.f;
#pragma unroll
      for (int reg = 0; reg < 16; ++reg) {
        const int r = (reg & 3) + 8 * (reg >> 2) + 4 * half;
        part += (r >= pos && r < end) ? v[reg] : 0.f;
      }
      part += __shfl_xor(part, 32, 64);  // combine the two half-wave row groups
      if (half == 0) atomicAdd(&out[(size_t)s * 256 + col], part);
      pos = end;
    }
  }
}

// ---------------------------------------------------------------------------
extern "C" void kernel_launch(void* const* d_in, const int* in_sizes, int n_in,
                              void* d_out, int out_size, void* d_ws, size_t ws_size,
                              hipStream_t stream) {
  const float* x  = (const float*)d_in[0];
  const int*   idx = (const int*)d_in[1];
  const float* W1 = (const float*)d_in[3];
  const float* b1 = (const float*)d_in[4];
  const float* W2 = (const float*)d_in[5];
  const float* b2 = (const float*)d_in[6];
  const float* Wt = (const float*)d_in[7];
  const float* bt = (const float*)d_in[8];
  float* out = (float*)d_out;

  const int N = in_sizes[0] / 256;
  const int S = out_size / 256;

  // ws layout: gate[N] f32 | e[N] f32 | denom[S] f32 | smax[S] u32   (~8.3 MB)
  float* gate = (float*)d_ws;
  float* e = gate + N;
  float* denom = e + N;
  unsigned* smax = (unsigned*)(denom + S);

  hipMemsetAsync(d_out, 0, (size_t)out_size * sizeof(float), stream);
  hipMemsetAsync(denom, 0, (size_t)S * sizeof(float), stream);
  hipMemsetAsync(smax, 0, (size_t)S * sizeof(unsigned), stream);

  gate_kernel<<<2048, 512, 0, stream>>>(x, W1, b1, W2, b2, gate, N / 64);
  const int sgrid = (N + 255) / 256;
  seg_max_kernel<<<sgrid, 256, 0, stream>>>(gate, idx, smax, N);
  seg_denom_kernel<<<sgrid, 256, 0, stream>>>(gate, idx, smax, e, denom, N);
  transform_kernel<<<2048, 512, 0, stream>>>(x, idx, Wt, bt, e, denom, out, N / 32);
}